// Round 11
// baseline (256.532 us; speedup 1.0000x reference)
//
#include <hip/hip_runtime.h>
#include <stdint.h>

#define NN 8192      // nodes per batch
#define EE 8191      // edges per batch
#define AD 256       // ADIM
#define BB 16        // batch

typedef unsigned short u16;
typedef short bf16x8 __attribute__((ext_vector_type(8)));
typedef float f32x4 __attribute__((ext_vector_type(4)));
typedef u16 u16x8 __attribute__((ext_vector_type(8)));

__device__ __forceinline__ u16 f2bf(float f) {
  unsigned u = __builtin_bit_cast(unsigned, f);
  u = u + 0x7fffu + ((u >> 16) & 1u);   // RNE
  return (u16)(u >> 16);
}

// ---------------------------------------------------------------------------
// prep_ma: Ma/bk/bias_all + folded vec weights Mw (verified R10).
// grid = 256, block = 256.
// ---------------------------------------------------------------------------
__global__ __launch_bounds__(256) void prep_ma(const float* __restrict__ W2,
                                               const float* __restrict__ b2,
                                               const float* __restrict__ K_a,
                                               const float* __restrict__ b_a,
                                               const float* __restrict__ W_v,
                                               const float* __restrict__ K_v,
                                               u16* __restrict__ Ma,
                                               float* __restrict__ bk,
                                               float* __restrict__ bias_all,
                                               float* __restrict__ Mw) {
  __shared__ float ka[256][4];
  __shared__ float b2s[256];
  __shared__ float red[4];
  const int tid = threadIdx.x;
  const int o = blockIdx.x;
  const float4 kv = ((const float4*)K_a)[(size_t)o * 256 + tid];
  ka[tid][0] = kv.x; ka[tid][1] = kv.y; ka[tid][2] = kv.z; ka[tid][3] = kv.w;
  b2s[tid] = b2[tid];
  __syncthreads();
  float acc[4] = {0.f, 0.f, 0.f, 0.f};
  for (int c = 0; c < 256; ++c) {
    const float w = W2[(c << 8) + tid];
    acc[0] += ka[c][0] * w; acc[1] += ka[c][1] * w;
    acc[2] += ka[c][2] * w; acc[3] += ka[c][3] * w;
  }
  const int ac = tid >> 6, ks = (tid >> 5) & 1, jj = tid & 31;
#pragma unroll
  for (int t = 0; t < 4; ++t)
    Ma[((size_t)((t * 8 + ac * 2 + ks) * 256 + o)) * 32 + jj] = f2bf(acc[t]);
  if (tid < 4) {
    float s = 0.f;
    for (int c = 0; c < 256; ++c) s += ka[c][tid] * b2s[c];
    bk[tid * 256 + o] = s;
    red[tid] = s;
  }
  __syncthreads();
  if (tid == 0) bias_all[o] = b_a[o] + red[0] + red[1] + red[2] + red[3];
  if (blockIdx.x == 0) {
    for (int pair = tid; pair < 512; pair += 256) {
      const int k = pair >> 7, ov = pair & 127;
      float c0 = 0.f, c1 = 0.f, c2 = 0.f, c3 = 0.f;
      for (int c = 0; c < 128; ++c) {
        const float kvv = K_v[(size_t)((ov << 7) + c) * 4 + k];
        const float4 wv = ((const float4*)W_v)[c];
        c0 += kvv * wv.x; c1 += kvv * wv.y; c2 += kvv * wv.z; c3 += kvv * wv.w;
      }
      float4 w;
      w.x = -(c0 + c3);   // coeff of pos0[e]
      w.y = c0 - c2;      // coeff of pos0[e+1]
      w.z = c2 - c1;      // coeff of pos1[e]
      w.w = c1 + c3;      // coeff of pos1[e+1]
      ((float4*)Mw)[pair] = w;
    }
  }
}

#define MM(Bf, Af, C) __builtin_amdgcn_mfma_f32_16x16x32_bf16((Bf), (Af), (C), 0, 0, 0)

// ---------------------------------------------------------------------------
// gemm_fused (1024 threads): 256n x 256o tile, 16 waves (4x4), wave = 64x64.
// Same verified hs swizzle + free-running K-loop; B ping-pong; af single-buf
// (latency hidden by 4 waves/SIMD). Vec phase: sliding-window, 32 nodes/thr.
// grid = 512, block = 1024, 1 block/CU (LDS 138KB), 16 waves/CU.
// ---------------------------------------------------------------------------
__global__ __launch_bounds__(1024, 4) void gemm_fused(const float* __restrict__ p0,
                                                      const float* __restrict__ p1,
                                                      const float* __restrict__ W1,
                                                      const float* __restrict__ b1,
                                                      const u16* __restrict__ Ma,
                                                      const float* __restrict__ bias_all,
                                                      const float* __restrict__ bk,
                                                      const float* __restrict__ Mw,
                                                      float* __restrict__ out) {
  __shared__ __align__(16) char hs[259 * 528];   // 136,752 B
  __shared__ float nrm[259][4];
  const int tid = threadIdx.x;
  const int lane = tid & 63;
  const int wid = tid >> 6;
  const int wm = wid >> 2, wn = wid & 3;   // 4x4 wave grid
  const int b = blockIdx.x >> 5;
  const int n0 = (blockIdx.x & 31) * 256;
  const int lhi = lane >> 4;
  const int llo = lane & 15;

  // --- norms for rows 0..258 (edge e = n0 + rr - 2) ---
  const size_t pbase = (size_t)b * NN * 3;
  for (int idx = tid; idx < 1036; idx += 1024) {
    const int rr = idx >> 2, i = idx & 3;
    const int e = n0 + rr - 2;
    float v = 0.f;
    if (e >= 0 && e < EE) {
      const float* P0 = p0 + pbase;
      const float* P1 = p1 + pbase;
      const float* hi = (i == 0) ? P0 + (size_t)(e + 1) * 3
                      : (i == 1) ? P1 + (size_t)(e + 1) * 3
                      : (i == 2) ? P1 + (size_t)e * 3
                                 : P1 + (size_t)(e + 1) * 3;
      const float* lo = (i == 0) ? P0 + (size_t)e * 3
                      : (i == 1) ? P1 + (size_t)e * 3
                      : (i == 2) ? P0 + (size_t)(e + 1) * 3
                                 : P0 + (size_t)e * 3;
      const float dx = hi[0] - lo[0], dy = hi[1] - lo[1], dz = hi[2] - lo[2];
      v = sqrtf(dx * dx + dy * dy + dz * dz);
    }
    nrm[rr][i] = v;
  }
  __syncthreads();

  // --- h tile (swizzled): chunk g8 of row rr -> (g8&24)|((g8+rr)&7) ---
  {
    const int g8 = tid & 31;
    const int strip = tid >> 5;   // 0..31
    float w1r[8][4], b1r[8];
    const float4* W14 = (const float4*)W1;
#pragma unroll
    for (int j = 0; j < 8; ++j) {
      const float4 w = W14[g8 * 8 + j];
      w1r[j][0] = w.x; w1r[j][1] = w.y; w1r[j][2] = w.z; w1r[j][3] = w.w;
      b1r[j] = b1[g8 * 8 + j];
    }
    for (int rr = strip; rr < 259; rr += 32) {
      const int e = n0 + rr - 2;
      const bool valid = (e >= 0) && (e < EE);
      const float nA = nrm[rr][0], nB = nrm[rr][1], nC = nrm[rr][2], nD = nrm[rr][3];
      u16x8 pack;
#pragma unroll
      for (int j = 0; j < 8; ++j) {
        float v = b1r[j] + nA * w1r[j][0] + nB * w1r[j][1] +
                  nC * w1r[j][2] + nD * w1r[j][3];
        v = (v >= 0.f) ? v : 0.2f * v;
        pack[j] = valid ? f2bf(v) : (u16)0;
      }
      const int cs = (g8 & 24) | ((g8 + rr) & 7);
      *(u16x8*)(hs + rr * 528 + (cs << 4)) = pack;
    }
  }
  __syncthreads();

  // ===== fused vec phase: 32 nodes/thread, sliding 8-row window ===========
  {
    const int o = tid & 127, ng = tid >> 7;   // ng 0..7
    const int nstart = n0 + ng * 32;
    const float4* Mw4 = (const float4*)Mw;
    const float4 w0 = Mw4[o], w1 = Mw4[128 + o],
                 w2 = Mw4[256 + o], w3 = Mw4[384 + o];
    float* vb = out + 33554432ULL + (((size_t)b * NN + nstart) * 128 + o) * 3;
    const float* P0 = p0 + pbase;
    const float* P1 = p1 + pbase;
    float Ra[8][3], Rp[8][3];
    // initial window: rows nstart-2 .. nstart+5 (clamped)
#pragma unroll
    for (int r = 0; r < 8; ++r) {
      int row = nstart - 2 + r;
      row = row < 0 ? 0 : (row > NN - 1 ? NN - 1 : row);
      const float* a = P0 + (size_t)row * 3;
      const float* p = P1 + (size_t)row * 3;
      Ra[r][0] = a[0]; Ra[r][1] = a[1]; Ra[r][2] = a[2];
      Rp[r][0] = p[0]; Rp[r][1] = p[1]; Rp[r][2] = p[2];
    }
#pragma unroll 1
    for (int jc = 0; jc < 8; ++jc) {
      const int nb = nstart + jc * 4;
#pragma unroll
      for (int jj = 0; jj < 4; ++jj) {
        const int n = nb + jj;
        float r0 = 0.f, r1 = 0.f, r2 = 0.f;
#pragma unroll
        for (int k = 0; k < 4; ++k) {
          if (n + k >= 2 && n + k <= NN) {   // 0 <= e <= EE-1 (wave-uniform)
            const float4 w = (k == 0) ? w0 : (k == 1) ? w1 : (k == 2) ? w2 : w3;
            r0 += w.x * Ra[jj + k][0] + w.y * Ra[jj + k + 1][0] +
                  w.z * Rp[jj + k][0] + w.w * Rp[jj + k + 1][0];
            r1 += w.x * Ra[jj + k][1] + w.y * Ra[jj + k + 1][1] +
                  w.z * Rp[jj + k][1] + w.w * Rp[jj + k + 1][1];
            r2 += w.x * Ra[jj + k][2] + w.y * Ra[jj + k + 1][2] +
                  w.z * Rp[jj + k][2] + w.w * Rp[jj + k + 1][2];
          }
        }
        float* dst = vb + (size_t)(jc * 4 + jj) * 384;
        dst[0] = r0; dst[1] = r1; dst[2] = r2;
      }
      if (jc < 7) {   // slide window by 4 rows
#pragma unroll
        for (int r = 0; r < 4; ++r) {
          Ra[r][0] = Ra[r + 4][0]; Ra[r][1] = Ra[r + 4][1]; Ra[r][2] = Ra[r + 4][2];
          Rp[r][0] = Rp[r + 4][0]; Rp[r][1] = Rp[r + 4][1]; Rp[r][2] = Rp[r + 4][2];
        }
#pragma unroll
        for (int r = 4; r < 8; ++r) {
          int row = nb + 2 + r;   // rows nb+6 .. nb+9
          row = row > NN - 1 ? NN - 1 : row;
          const float* a = P0 + (size_t)row * 3;
          const float* p = P1 + (size_t)row * 3;
          Ra[r][0] = a[0]; Ra[r][1] = a[1]; Ra[r][2] = a[2];
          Rp[r][0] = p[0]; Rp[r][1] = p[1]; Rp[r][2] = p[2];
        }
      }
    }
  }
  // ==== end vec phase (stores drain under K-loop) =========================

  const f32x4 zero = {0.f, 0.f, 0.f, 0.f};
  f32x4 acc[4][4];
#pragma unroll
  for (int m = 0; m < 4; ++m)
#pragma unroll
    for (int nf = 0; nf < 4; ++nf) acc[m][nf] = zero;

  const char* mb = (const char*)Ma + (size_t)(wn * 64 + llo) * 64 + (size_t)lhi * 16;
  const int rb = wm * 64 + llo;          // wave row base
  const int lt = llo + lhi;              // swizzle lane term

  bf16x8 pA0, pA1, pA2, pA3, pB0, pB1, pB2, pB3;
  pA0 = *(const bf16x8*)(mb);
  pA1 = *(const bf16x8*)(mb + 1024);
  pA2 = *(const bf16x8*)(mb + 2048);
  pA3 = *(const bf16x8*)(mb + 3072);

#pragma unroll 1
  for (int s = 0; s < 32; s += 2) {
    const int tap = s >> 3;
    const int q = (s >> 1) & 3;
    const int swe = (lt + tap) & 7;
    const char* rowp = hs + (rb + tap) * 528 + (q << 7);
    const char* ape = rowp + (swe << 4);            // ks=0
    const char* apo = rowp + ((swe ^ 4) << 4);      // ks=1
    // --- even step s (uses pA) ---
    {
      const char* bp = mb + (size_t)(s + 1) * 16384;   // prefetch B(s+1)
      pB0 = *(const bf16x8*)(bp);
      pB1 = *(const bf16x8*)(bp + 1024);
      pB2 = *(const bf16x8*)(bp + 2048);
      pB3 = *(const bf16x8*)(bp + 3072);
      bf16x8 af0 = *(const bf16x8*)(ape);
      bf16x8 af1 = *(const bf16x8*)(ape + 8448);
      bf16x8 af2 = *(const bf16x8*)(ape + 16896);
      bf16x8 af3 = *(const bf16x8*)(ape + 25344);
      acc[0][0] = MM(pA0, af0, acc[0][0]); acc[1][0] = MM(pA0, af1, acc[1][0]);
      acc[2][0] = MM(pA0, af2, acc[2][0]); acc[3][0] = MM(pA0, af3, acc[3][0]);
      acc[0][1] = MM(pA1, af0, acc[0][1]); acc[1][1] = MM(pA1, af1, acc[1][1]);
      acc[2][1] = MM(pA1, af2, acc[2][1]); acc[3][1] = MM(pA1, af3, acc[3][1]);
      acc[0][2] = MM(pA2, af0, acc[0][2]); acc[1][2] = MM(pA2, af1, acc[1][2]);
      acc[2][2] = MM(pA2, af2, acc[2][2]); acc[3][2] = MM(pA2, af3, acc[3][2]);
      acc[0][3] = MM(pA3, af0, acc[0][3]); acc[1][3] = MM(pA3, af1, acc[1][3]);
      acc[2][3] = MM(pA3, af2, acc[2][3]); acc[3][3] = MM(pA3, af3, acc[3][3]);
    }
    // --- odd step s+1 (uses pB) ---
    {
      const int sp = (s + 2 < 32) ? (s + 2) : 31;
      const char* bp = mb + (size_t)sp * 16384;        // prefetch B(s+2)
      pA0 = *(const bf16x8*)(bp);
      pA1 = *(const bf16x8*)(bp + 1024);
      pA2 = *(const bf16x8*)(bp + 2048);
      pA3 = *(const bf16x8*)(bp + 3072);
      bf16x8 af0 = *(const bf16x8*)(apo);
      bf16x8 af1 = *(const bf16x8*)(apo + 8448);
      bf16x8 af2 = *(const bf16x8*)(apo + 16896);
      bf16x8 af3 = *(const bf16x8*)(apo + 25344);
      acc[0][0] = MM(pB0, af0, acc[0][0]); acc[1][0] = MM(pB0, af1, acc[1][0]);
      acc[2][0] = MM(pB0, af2, acc[2][0]); acc[3][0] = MM(pB0, af3, acc[3][0]);
      acc[0][1] = MM(pB1, af0, acc[0][1]); acc[1][1] = MM(pB1, af1, acc[1][1]);
      acc[2][1] = MM(pB1, af2, acc[2][1]); acc[3][1] = MM(pB1, af3, acc[3][1]);
      acc[0][2] = MM(pB2, af0, acc[0][2]); acc[1][2] = MM(pB2, af1, acc[1][2]);
      acc[2][2] = MM(pB2, af2, acc[2][2]); acc[3][2] = MM(pB2, af3, acc[3][2]);
      acc[0][3] = MM(pB3, af0, acc[0][3]); acc[1][3] = MM(pB3, af1, acc[1][3]);
      acc[2][3] = MM(pB3, af2, acc[2][3]); acc[3][3] = MM(pB3, af3, acc[3][3]);
    }
  }

  // --- epilogue: D row = o (lhi*4+j), col = node (llo); fixup folded ---
#pragma unroll
  for (int m = 0; m < 4; ++m) {
    const int node = n0 + wm * 64 + m * 16 + llo;
    float* orow = out + ((size_t)b * NN + node) * AD;
    const bool edge = (node <= 1) | (node >= NN - 2);
#pragma unroll
    for (int nf = 0; nf < 4; ++nf) {
      const int o0 = wn * 64 + nf * 16 + lhi * 4;
      float bx = bias_all[o0], by = bias_all[o0 + 1],
            bz = bias_all[o0 + 2], bw = bias_all[o0 + 3];
      if (edge) {
        const float* k0 = bk + o0;
        const float* k1 = bk + 256 + o0;
        const float* k2 = bk + 512 + o0;
        const float* k3 = bk + 768 + o0;
        if (node == 0) {
          bx -= k0[0] + k1[0]; by -= k0[1] + k1[1];
          bz -= k0[2] + k1[2]; bw -= k0[3] + k1[3];
        } else if (node == 1) {
          bx -= k0[0]; by -= k0[1]; bz -= k0[2]; bw -= k0[3];
        } else if (node == NN - 2) {
          bx -= k3[0]; by -= k3[1]; bz -= k3[2]; bw -= k3[3];
        } else {
          bx -= k2[0] + k3[0]; by -= k2[1] + k3[1];
          bz -= k2[2] + k3[2]; bw -= k2[3] + k3[3];
        }
      }
      float4 st;
      st.x = acc[m][nf][0] + bx;
      st.y = acc[m][nf][1] + by;
      st.z = acc[m][nf][2] + bz;
      st.w = acc[m][nf][3] + bw;
      *(float4*)(orow + o0) = st;
    }
  }
}

// ---------------------------------------------------------------------------
extern "C" void kernel_launch(void* const* d_in, const int* in_sizes, int n_in,
                              void* d_out, int out_size, void* d_ws, size_t ws_size,
                              hipStream_t stream) {
  const float* pos_0 = (const float*)d_in[0];
  const float* pos_1 = (const float*)d_in[1];
  const float* W_v = (const float*)d_in[2];
  const float* W1 = (const float*)d_in[3];
  const float* b1 = (const float*)d_in[4];
  const float* W2 = (const float*)d_in[5];
  const float* b2 = (const float*)d_in[6];
  const float* K_a = (const float*)d_in[7];
  const float* b_a = (const float*)d_in[8];
  const float* K_v = (const float*)d_in[9];
  float* out = (float*)d_out;
  char* ws = (char*)d_ws;

  const size_t MA_BYTES = (size_t)32 * 256 * 32 * 2;    // 524,288
  u16* Ma = (u16*)(ws);
  float* bk = (float*)(ws + MA_BYTES);
  float* bias_all = (float*)(ws + MA_BYTES + 4096);
  float* Mw = (float*)(ws + MA_BYTES + 4096 + 1024);

  prep_ma<<<dim3(256), dim3(256), 0, stream>>>(W2, b2, K_a, b_a, W_v, K_v,
                                               Ma, bk, bias_all, Mw);
  gemm_fused<<<dim3(512), dim3(1024), 0, stream>>>(pos_0, pos_1, W1, b1, Ma,
                                                   bias_all, bk, Mw, out);
}

// Round 13
// 174.753 us; speedup vs baseline: 1.4680x; 1.4680x over previous
//
#include <hip/hip_runtime.h>
#include <stdint.h>

#define NN 8192      // nodes per batch
#define EE 8191      // edges per batch
#define AD 256       // ADIM
#define BB 16        // batch

typedef unsigned short u16;
typedef short bf16x8 __attribute__((ext_vector_type(8)));
typedef float f32x4 __attribute__((ext_vector_type(4)));
typedef u16 u16x8 __attribute__((ext_vector_type(8)));

__device__ __forceinline__ u16 f2bf(float f) {
  unsigned u = __builtin_bit_cast(unsigned, f);
  u = u + 0x7fffu + ((u >> 16) & 1u);   // RNE
  return (u16)(u >> 16);
}

// ---------------------------------------------------------------------------
// prep_ma: Ma/bk/bias_all + folded vec weights Mw (verified).
// grid = 256, block = 256.
// ---------------------------------------------------------------------------
__global__ __launch_bounds__(256) void prep_ma(const float* __restrict__ W2,
                                               const float* __restrict__ b2,
                                               const float* __restrict__ K_a,
                                               const float* __restrict__ b_a,
                                               const float* __restrict__ W_v,
                                               const float* __restrict__ K_v,
                                               u16* __restrict__ Ma,
                                               float* __restrict__ bk,
                                               float* __restrict__ bias_all,
                                               float* __restrict__ Mw) {
  __shared__ float ka[256][4];
  __shared__ float b2s[256];
  __shared__ float red[4];
  const int tid = threadIdx.x;
  const int o = blockIdx.x;
  const float4 kv = ((const float4*)K_a)[(size_t)o * 256 + tid];
  ka[tid][0] = kv.x; ka[tid][1] = kv.y; ka[tid][2] = kv.z; ka[tid][3] = kv.w;
  b2s[tid] = b2[tid];
  __syncthreads();
  float acc[4] = {0.f, 0.f, 0.f, 0.f};
  for (int c = 0; c < 256; ++c) {
    const float w = W2[(c << 8) + tid];
    acc[0] += ka[c][0] * w; acc[1] += ka[c][1] * w;
    acc[2] += ka[c][2] * w; acc[3] += ka[c][3] * w;
  }
  const int ac = tid >> 6, ks = (tid >> 5) & 1, jj = tid & 31;
#pragma unroll
  for (int t = 0; t < 4; ++t)
    Ma[((size_t)((t * 8 + ac * 2 + ks) * 256 + o)) * 32 + jj] = f2bf(acc[t]);
  if (tid < 4) {
    float s = 0.f;
    for (int c = 0; c < 256; ++c) s += ka[c][tid] * b2s[c];
    bk[tid * 256 + o] = s;
    red[tid] = s;
  }
  __syncthreads();
  if (tid == 0) bias_all[o] = b_a[o] + red[0] + red[1] + red[2] + red[3];
  if (blockIdx.x == 0) {
    for (int pair = tid; pair < 512; pair += 256) {
      const int k = pair >> 7, ov = pair & 127;
      float c0 = 0.f, c1 = 0.f, c2 = 0.f, c3 = 0.f;
      for (int c = 0; c < 128; ++c) {
        const float kvv = K_v[(size_t)((ov << 7) + c) * 4 + k];
        const float4 wv = ((const float4*)W_v)[c];
        c0 += kvv * wv.x; c1 += kvv * wv.y; c2 += kvv * wv.z; c3 += kvv * wv.w;
      }
      float4 w;
      w.x = -(c0 + c3);   // coeff of pos0[e]
      w.y = c0 - c2;      // coeff of pos0[e+1]
      w.z = c2 - c1;      // coeff of pos1[e]
      w.w = c1 + c3;      // coeff of pos1[e+1]
      ((float4*)Mw)[pair] = w;
    }
  }
}

#define MM(Bf, Af, C) __builtin_amdgcn_mfma_f32_16x16x32_bf16((Bf), (Af), (C), 0, 0, 0)

// ---------------------------------------------------------------------------
// gemm_fused: R10 structure (512 thr, 8 waves of 128n x 64o, hs swizzle +
// af pipeline) with NON-TEMPORAL output stores so the 335 MB of writes do
// not evict Ma/pos from L2 during the K-loop (R11 counters: FETCH=152MB of
// Ma re-fetch caused by store-stream eviction).
// grid = 16*32 = 512, block = 512.
// ---------------------------------------------------------------------------
__global__ __launch_bounds__(512, 2) void gemm_fused(const float* __restrict__ p0,
                                                     const float* __restrict__ p1,
                                                     const float* __restrict__ W1,
                                                     const float* __restrict__ b1,
                                                     const u16* __restrict__ Ma,
                                                     const float* __restrict__ bias_all,
                                                     const float* __restrict__ bk,
                                                     const float* __restrict__ Mw,
                                                     float* __restrict__ out) {
  __shared__ __align__(16) char hs[259 * 528];
  __shared__ float nrm[259][4];
  const int tid = threadIdx.x;
  const int lane = tid & 63;
  const int wid = tid >> 6;
  const int wm = wid >> 2, wn = wid & 3;
  const int b = blockIdx.x >> 5;
  const int n0 = (blockIdx.x & 31) * 256;
  const int lhi = lane >> 4;
  const int llo = lane & 15;

  // --- norms for rows 0..258 (edge e = n0 + rr - 2) ---
  const size_t pbase = (size_t)b * NN * 3;
  for (int idx = tid; idx < 1036; idx += 512) {
    const int rr = idx >> 2, i = idx & 3;
    const int e = n0 + rr - 2;
    float v = 0.f;
    if (e >= 0 && e < EE) {
      const float* P0 = p0 + pbase;
      const float* P1 = p1 + pbase;
      const float* hi = (i == 0) ? P0 + (size_t)(e + 1) * 3
                      : (i == 1) ? P1 + (size_t)(e + 1) * 3
                      : (i == 2) ? P1 + (size_t)e * 3
                                 : P1 + (size_t)(e + 1) * 3;
      const float* lo = (i == 0) ? P0 + (size_t)e * 3
                      : (i == 1) ? P1 + (size_t)e * 3
                      : (i == 2) ? P0 + (size_t)(e + 1) * 3
                                 : P0 + (size_t)e * 3;
      const float dx = hi[0] - lo[0], dy = hi[1] - lo[1], dz = hi[2] - lo[2];
      v = sqrtf(dx * dx + dy * dy + dz * dz);
    }
    nrm[rr][i] = v;
  }
  __syncthreads();

  // --- h tile (swizzled store): chunk g8 of row rr -> (g8&24)|((g8+rr)&7) ---
  {
    const int g8 = tid & 31;
    const int strip = tid >> 5;
    float w1r[8][4], b1r[8];
    const float4* W14 = (const float4*)W1;
#pragma unroll
    for (int j = 0; j < 8; ++j) {
      const float4 w = W14[g8 * 8 + j];
      w1r[j][0] = w.x; w1r[j][1] = w.y; w1r[j][2] = w.z; w1r[j][3] = w.w;
      b1r[j] = b1[g8 * 8 + j];
    }
    for (int rr = strip; rr < 259; rr += 16) {
      const int e = n0 + rr - 2;
      const bool valid = (e >= 0) && (e < EE);
      const float nA = nrm[rr][0], nB = nrm[rr][1], nC = nrm[rr][2], nD = nrm[rr][3];
      u16x8 pack;
#pragma unroll
      for (int j = 0; j < 8; ++j) {
        float v = b1r[j] + nA * w1r[j][0] + nB * w1r[j][1] +
                  nC * w1r[j][2] + nD * w1r[j][3];
        v = (v >= 0.f) ? v : 0.2f * v;
        pack[j] = valid ? f2bf(v) : (u16)0;
      }
      const int cs = (g8 & 24) | ((g8 + rr) & 7);
      *(u16x8*)(hs + rr * 528 + (cs << 4)) = pack;
    }
  }
  __syncthreads();

  // ===== fused vec phase: v_out for nodes n0..n0+255, o = tid&127 =========
  // NT stores: output never re-read; keep Ma/pos resident in L2.
  {
    const int o = tid & 127, ng = tid >> 7;
    const int nstart = n0 + ng * 64;
    const float4* Mw4 = (const float4*)Mw;
    const float4 w0 = Mw4[o], w1 = Mw4[128 + o],
                 w2 = Mw4[256 + o], w3 = Mw4[384 + o];
    float* vb = out + 33554432ULL + (((size_t)b * NN + nstart) * 128 + o) * 3;
    const float* P0 = p0 + pbase;
    const float* P1 = p1 + pbase;
    float Ra[8][3], Rp[8][3];
#pragma unroll
    for (int r = 0; r < 8; ++r) {
      int row = nstart - 2 + r;
      row = row < 0 ? 0 : (row > NN - 1 ? NN - 1 : row);
      const float* a = P0 + (size_t)row * 3;
      const float* p = P1 + (size_t)row * 3;
      Ra[r][0] = a[0]; Ra[r][1] = a[1]; Ra[r][2] = a[2];
      Rp[r][0] = p[0]; Rp[r][1] = p[1]; Rp[r][2] = p[2];
    }
#pragma unroll 1
    for (int jc = 0; jc < 16; ++jc) {
      const int nb = nstart + jc * 4;
#pragma unroll
      for (int jj = 0; jj < 4; ++jj) {
        const int n = nb + jj;
        float r0 = 0.f, r1 = 0.f, r2 = 0.f;
#pragma unroll
        for (int k = 0; k < 4; ++k) {
          if (n + k >= 2 && n + k <= NN) {   // 0 <= e <= EE-1
            const float4 w = (k == 0) ? w0 : (k == 1) ? w1 : (k == 2) ? w2 : w3;
            r0 += w.x * Ra[jj + k][0] + w.y * Ra[jj + k + 1][0] +
                  w.z * Rp[jj + k][0] + w.w * Rp[jj + k + 1][0];
            r1 += w.x * Ra[jj + k][1] + w.y * Ra[jj + k + 1][1] +
                  w.z * Rp[jj + k][1] + w.w * Rp[jj + k + 1][1];
            r2 += w.x * Ra[jj + k][2] + w.y * Ra[jj + k + 1][2] +
                  w.z * Rp[jj + k][2] + w.w * Rp[jj + k + 1][2];
          }
        }
        float* dst = vb + (size_t)(jc * 4 + jj) * 384;
        __builtin_nontemporal_store(r0, dst + 0);
        __builtin_nontemporal_store(r1, dst + 1);
        __builtin_nontemporal_store(r2, dst + 2);
      }
      if (jc < 15) {   // slide window by 4 rows
#pragma unroll
        for (int r = 0; r < 4; ++r) {
          Ra[r][0] = Ra[r + 4][0]; Ra[r][1] = Ra[r + 4][1]; Ra[r][2] = Ra[r + 4][2];
          Rp[r][0] = Rp[r + 4][0]; Rp[r][1] = Rp[r + 4][1]; Rp[r][2] = Rp[r + 4][2];
        }
#pragma unroll
        for (int r = 4; r < 8; ++r) {
          int row = nb + 2 + r;   // rows nb+6 .. nb+9
          row = row > NN - 1 ? NN - 1 : row;
          const float* a = P0 + (size_t)row * 3;
          const float* p = P1 + (size_t)row * 3;
          Ra[r][0] = a[0]; Ra[r][1] = a[1]; Ra[r][2] = a[2];
          Rp[r][0] = p[0]; Rp[r][1] = p[1]; Rp[r][2] = p[2];
        }
      }
    }
  }
  // ==== end vec phase (NT stores drain under K-loop) ======================

  const f32x4 zero = {0.f, 0.f, 0.f, 0.f};
  f32x4 acc[8][4];
#pragma unroll
  for (int m = 0; m < 8; ++m)
#pragma unroll
    for (int nf = 0; nf < 4; ++nf) acc[m][nf] = zero;

  const char* mb = (const char*)Ma + (size_t)(wn * 64 + llo) * 64 + (size_t)lhi * 16;
  const int rb = wm * 128 + llo;
  const int lt = llo + lhi;

  bf16x8 pA0, pA1, pA2, pA3, pB0, pB1, pB2, pB3;
  pA0 = *(const bf16x8*)(mb);
  pA1 = *(const bf16x8*)(mb + 1024);
  pA2 = *(const bf16x8*)(mb + 2048);
  pA3 = *(const bf16x8*)(mb + 3072);

  bf16x8 afA0, afA1, afA2, afA3, afB0, afB1, afB2, afB3;
  {
    const char* ap = hs + rb * 528 + (((lt) & 7) << 4);
    afA0 = *(const bf16x8*)(ap);
    afA1 = *(const bf16x8*)(ap + 8448);
    afA2 = *(const bf16x8*)(ap + 16896);
    afA3 = *(const bf16x8*)(ap + 25344);
  }

#pragma unroll 1
  for (int s = 0; s < 32; s += 2) {
    const int tap = s >> 3;
    const int q = (s >> 1) & 3;
    const int swe = (lt + tap) & 7;
    const char* rowp = hs + (rb + tap) * 528 + (q << 7);
    const char* ape = rowp + (swe << 4);
    const char* apo = rowp + ((swe ^ 4) << 4);
    {
      const char* bp = mb + (size_t)(s + 1) * 16384;
      pB0 = *(const bf16x8*)(bp);
      pB1 = *(const bf16x8*)(bp + 1024);
      pB2 = *(const bf16x8*)(bp + 2048);
      pB3 = *(const bf16x8*)(bp + 3072);
      afB0 = *(const bf16x8*)(ape + 33792);
      afB1 = *(const bf16x8*)(ape + 42240);
      afB2 = *(const bf16x8*)(ape + 50688);
      afB3 = *(const bf16x8*)(ape + 59136);
      acc[0][0] = MM(pA0, afA0, acc[0][0]); acc[1][0] = MM(pA0, afA1, acc[1][0]);
      acc[2][0] = MM(pA0, afA2, acc[2][0]); acc[3][0] = MM(pA0, afA3, acc[3][0]);
      acc[0][1] = MM(pA1, afA0, acc[0][1]); acc[1][1] = MM(pA1, afA1, acc[1][1]);
      acc[2][1] = MM(pA1, afA2, acc[2][1]); acc[3][1] = MM(pA1, afA3, acc[3][1]);
      acc[0][2] = MM(pA2, afA0, acc[0][2]); acc[1][2] = MM(pA2, afA1, acc[1][2]);
      acc[2][2] = MM(pA2, afA2, acc[2][2]); acc[3][2] = MM(pA2, afA3, acc[3][2]);
      acc[0][3] = MM(pA3, afA0, acc[0][3]); acc[1][3] = MM(pA3, afA1, acc[1][3]);
      acc[2][3] = MM(pA3, afA2, acc[2][3]); acc[3][3] = MM(pA3, afA3, acc[3][3]);
      afA0 = *(const bf16x8*)(apo);
      afA1 = *(const bf16x8*)(apo + 8448);
      afA2 = *(const bf16x8*)(apo + 16896);
      afA3 = *(const bf16x8*)(apo + 25344);
      acc[4][0] = MM(pA0, afB0, acc[4][0]); acc[5][0] = MM(pA0, afB1, acc[5][0]);
      acc[6][0] = MM(pA0, afB2, acc[6][0]); acc[7][0] = MM(pA0, afB3, acc[7][0]);
      acc[4][1] = MM(pA1, afB0, acc[4][1]); acc[5][1] = MM(pA1, afB1, acc[5][1]);
      acc[6][1] = MM(pA1, afB2, acc[6][1]); acc[7][1] = MM(pA1, afB3, acc[7][1]);
      acc[4][2] = MM(pA2, afB0, acc[4][2]); acc[5][2] = MM(pA2, afB1, acc[5][2]);
      acc[6][2] = MM(pA2, afB2, acc[6][2]); acc[7][2] = MM(pA2, afB3, acc[7][2]);
      acc[4][3] = MM(pA3, afB0, acc[4][3]); acc[5][3] = MM(pA3, afB1, acc[5][3]);
      acc[6][3] = MM(pA3, afB2, acc[6][3]); acc[7][3] = MM(pA3, afB3, acc[7][3]);
    }
    {
      const int s2 = (s + 2) & 31;
      const char* bp = mb + (size_t)s2 * 16384;
      pA0 = *(const bf16x8*)(bp);
      pA1 = *(const bf16x8*)(bp + 1024);
      pA2 = *(const bf16x8*)(bp + 2048);
      pA3 = *(const bf16x8*)(bp + 3072);
      afB0 = *(const bf16x8*)(apo + 33792);
      afB1 = *(const bf16x8*)(apo + 42240);
      afB2 = *(const bf16x8*)(apo + 50688);
      afB3 = *(const bf16x8*)(apo + 59136);
      acc[0][0] = MM(pB0, afA0, acc[0][0]); acc[1][0] = MM(pB0, afA1, acc[1][0]);
      acc[2][0] = MM(pB0, afA2, acc[2][0]); acc[3][0] = MM(pB0, afA3, acc[3][0]);
      acc[0][1] = MM(pB1, afA0, acc[0][1]); acc[1][1] = MM(pB1, afA1, acc[1][1]);
      acc[2][1] = MM(pB1, afA2, acc[2][1]); acc[3][1] = MM(pB1, afA3, acc[3][1]);
      acc[0][2] = MM(pB2, afA0, acc[0][2]); acc[1][2] = MM(pB2, afA1, acc[1][2]);
      acc[2][2] = MM(pB2, afA2, acc[2][2]); acc[3][2] = MM(pB2, afA3, acc[3][2]);
      acc[0][3] = MM(pB3, afA0, acc[0][3]); acc[1][3] = MM(pB3, afA1, acc[1][3]);
      acc[2][3] = MM(pB3, afA2, acc[2][3]); acc[3][3] = MM(pB3, afA3, acc[3][3]);
      {
        const int tap2 = s2 >> 3;
        const int q2 = (s2 >> 1) & 3;
        const char* ap2 = hs + (rb + tap2) * 528 + (q2 << 7) +
                          ((((lt + tap2) & 7)) << 4);
        afA0 = *(const bf16x8*)(ap2);
        afA1 = *(const bf16x8*)(ap2 + 8448);
        afA2 = *(const bf16x8*)(ap2 + 16896);
        afA3 = *(const bf16x8*)(ap2 + 25344);
      }
      acc[4][0] = MM(pB0, afB0, acc[4][0]); acc[5][0] = MM(pB0, afB1, acc[5][0]);
      acc[6][0] = MM(pB0, afB2, acc[6][0]); acc[7][0] = MM(pB0, afB3, acc[7][0]);
      acc[4][1] = MM(pB1, afB0, acc[4][1]); acc[5][1] = MM(pB1, afB1, acc[5][1]);
      acc[6][1] = MM(pB1, afB2, acc[6][1]); acc[7][1] = MM(pB1, afB3, acc[7][1]);
      acc[4][2] = MM(pB2, afB0, acc[4][2]); acc[5][2] = MM(pB2, afB1, acc[5][2]);
      acc[6][2] = MM(pB2, afB2, acc[6][2]); acc[7][2] = MM(pB2, afB3, acc[7][2]);
      acc[4][3] = MM(pB3, afB0, acc[4][3]); acc[5][3] = MM(pB3, afB1, acc[5][3]);
      acc[6][3] = MM(pB3, afB2, acc[6][3]); acc[7][3] = MM(pB3, afB3, acc[7][3]);
    }
  }

#pragma unroll
  for (int m = 0; m < 8; ++m) {
    const int node = n0 + wm * 128 + m * 16 + llo;
    float* orow = out + ((size_t)b * NN + node) * AD;
    const bool edge = (node <= 1) | (node >= NN - 2);
#pragma unroll
    for (int nf = 0; nf < 4; ++nf) {
      const int o0 = wn * 64 + nf * 16 + lhi * 4;
      float bx = bias_all[o0], by = bias_all[o0 + 1],
            bz = bias_all[o0 + 2], bw = bias_all[o0 + 3];
      if (edge) {
        const float* k0 = bk + o0;
        const float* k1 = bk + 256 + o0;
        const float* k2 = bk + 512 + o0;
        const float* k3 = bk + 768 + o0;
        if (node == 0) {
          bx -= k0[0] + k1[0]; by -= k0[1] + k1[1];
          bz -= k0[2] + k1[2]; bw -= k0[3] + k1[3];
        } else if (node == 1) {
          bx -= k0[0]; by -= k0[1]; bz -= k0[2]; bw -= k0[3];
        } else if (node == NN - 2) {
          bx -= k3[0]; by -= k3[1]; bz -= k3[2]; bw -= k3[3];
        } else {
          bx -= k2[0] + k3[0]; by -= k2[1] + k3[1];
          bz -= k2[2] + k3[2]; bw -= k2[3] + k3[3];
        }
      }
      f32x4 st;
      st[0] = acc[m][nf][0] + bx;
      st[1] = acc[m][nf][1] + by;
      st[2] = acc[m][nf][2] + bz;
      st[3] = acc[m][nf][3] + bw;
      __builtin_nontemporal_store(st, (f32x4*)(orow + o0));
    }
  }
}

// ---------------------------------------------------------------------------
extern "C" void kernel_launch(void* const* d_in, const int* in_sizes, int n_in,
                              void* d_out, int out_size, void* d_ws, size_t ws_size,
                              hipStream_t stream) {
  const float* pos_0 = (const float*)d_in[0];
  const float* pos_1 = (const float*)d_in[1];
  const float* W_v = (const float*)d_in[2];
  const float* W1 = (const float*)d_in[3];
  const float* b1 = (const float*)d_in[4];
  const float* W2 = (const float*)d_in[5];
  const float* b2 = (const float*)d_in[6];
  const float* K_a = (const float*)d_in[7];
  const float* b_a = (const float*)d_in[8];
  const float* K_v = (const float*)d_in[9];
  float* out = (float*)d_out;
  char* ws = (char*)d_ws;

  const size_t MA_BYTES = (size_t)32 * 256 * 32 * 2;    // 524,288
  u16* Ma = (u16*)(ws);
  float* bk = (float*)(ws + MA_BYTES);
  float* bias_all = (float*)(ws + MA_BYTES + 4096);
  float* Mw = (float*)(ws + MA_BYTES + 4096 + 1024);

  prep_ma<<<dim3(256), dim3(256), 0, stream>>>(W2, b2, K_a, b_a, W_v, K_v,
                                               Ma, bk, bias_all, Mw);
  gemm_fused<<<dim3(512), dim3(512), 0, stream>>>(pos_0, pos_1, W1, b1, Ma,
                                                  bias_all, bk, Mw, out);
}

// Round 14
// 168.757 us; speedup vs baseline: 1.5201x; 1.0355x over previous
//
#include <hip/hip_runtime.h>
#include <stdint.h>

#define NN 8192      // nodes per batch
#define EE 8191      // edges per batch
#define AD 256       // ADIM
#define BB 16        // batch

typedef unsigned short u16;
typedef short bf16x8 __attribute__((ext_vector_type(8)));
typedef float f32x4 __attribute__((ext_vector_type(4)));
typedef u16 u16x8 __attribute__((ext_vector_type(8)));

__device__ __forceinline__ u16 f2bf(float f) {
  unsigned u = __builtin_bit_cast(unsigned, f);
  u = u + 0x7fffu + ((u >> 16) & 1u);   // RNE
  return (u16)(u >> 16);
}

// ---------------------------------------------------------------------------
// prep_ma: Ma/bk/bias_all + folded vec weights Mw (verified).
// grid = 256, block = 256.
// ---------------------------------------------------------------------------
__global__ __launch_bounds__(256) void prep_ma(const float* __restrict__ W2,
                                               const float* __restrict__ b2,
                                               const float* __restrict__ K_a,
                                               const float* __restrict__ b_a,
                                               const float* __restrict__ W_v,
                                               const float* __restrict__ K_v,
                                               u16* __restrict__ Ma,
                                               float* __restrict__ bk,
                                               float* __restrict__ bias_all,
                                               float* __restrict__ Mw) {
  __shared__ float ka[256][4];
  __shared__ float b2s[256];
  __shared__ float red[4];
  const int tid = threadIdx.x;
  const int o = blockIdx.x;
  const float4 kv = ((const float4*)K_a)[(size_t)o * 256 + tid];
  ka[tid][0] = kv.x; ka[tid][1] = kv.y; ka[tid][2] = kv.z; ka[tid][3] = kv.w;
  b2s[tid] = b2[tid];
  __syncthreads();
  float acc[4] = {0.f, 0.f, 0.f, 0.f};
  for (int c = 0; c < 256; ++c) {
    const float w = W2[(c << 8) + tid];
    acc[0] += ka[c][0] * w; acc[1] += ka[c][1] * w;
    acc[2] += ka[c][2] * w; acc[3] += ka[c][3] * w;
  }
  const int ac = tid >> 6, ks = (tid >> 5) & 1, jj = tid & 31;
#pragma unroll
  for (int t = 0; t < 4; ++t)
    Ma[((size_t)((t * 8 + ac * 2 + ks) * 256 + o)) * 32 + jj] = f2bf(acc[t]);
  if (tid < 4) {
    float s = 0.f;
    for (int c = 0; c < 256; ++c) s += ka[c][tid] * b2s[c];
    bk[tid * 256 + o] = s;
    red[tid] = s;
  }
  __syncthreads();
  if (tid == 0) bias_all[o] = b_a[o] + red[0] + red[1] + red[2] + red[3];
  if (blockIdx.x == 0) {
    for (int pair = tid; pair < 512; pair += 256) {
      const int k = pair >> 7, ov = pair & 127;
      float c0 = 0.f, c1 = 0.f, c2 = 0.f, c3 = 0.f;
      for (int c = 0; c < 128; ++c) {
        const float kvv = K_v[(size_t)((ov << 7) + c) * 4 + k];
        const float4 wv = ((const float4*)W_v)[c];
        c0 += kvv * wv.x; c1 += kvv * wv.y; c2 += kvv * wv.z; c3 += kvv * wv.w;
      }
      float4 w;
      w.x = -(c0 + c3);   // coeff of pos0[e]
      w.y = c0 - c2;      // coeff of pos0[e+1]
      w.z = c2 - c1;      // coeff of pos1[e]
      w.w = c1 + c3;      // coeff of pos1[e+1]
      ((float4*)Mw)[pair] = w;
    }
  }
}

#define MM(Bf, Af, C) __builtin_amdgcn_mfma_f32_16x16x32_bf16((Bf), (Af), (C), 0, 0, 0)

// ---------------------------------------------------------------------------
// gemm_a: R13 structure WITHOUT the fused vec phase (512 thr, 8 waves of
// 128n x 64o, hs swizzle + af pipeline, NT epilogue stores).
// grid = 16*32 = 512, block = 512.
// ---------------------------------------------------------------------------
__global__ __launch_bounds__(512, 2) void gemm_a(const float* __restrict__ p0,
                                                 const float* __restrict__ p1,
                                                 const float* __restrict__ W1,
                                                 const float* __restrict__ b1,
                                                 const u16* __restrict__ Ma,
                                                 const float* __restrict__ bias_all,
                                                 const float* __restrict__ bk,
                                                 float* __restrict__ out) {
  __shared__ __align__(16) char hs[259 * 528];
  __shared__ float nrm[259][4];
  const int tid = threadIdx.x;
  const int lane = tid & 63;
  const int wid = tid >> 6;
  const int wm = wid >> 2, wn = wid & 3;
  const int b = blockIdx.x >> 5;
  const int n0 = (blockIdx.x & 31) * 256;
  const int lhi = lane >> 4;
  const int llo = lane & 15;

  // --- norms for rows 0..258 (edge e = n0 + rr - 2) ---
  const size_t pbase = (size_t)b * NN * 3;
  for (int idx = tid; idx < 1036; idx += 512) {
    const int rr = idx >> 2, i = idx & 3;
    const int e = n0 + rr - 2;
    float v = 0.f;
    if (e >= 0 && e < EE) {
      const float* P0 = p0 + pbase;
      const float* P1 = p1 + pbase;
      const float* hi = (i == 0) ? P0 + (size_t)(e + 1) * 3
                      : (i == 1) ? P1 + (size_t)(e + 1) * 3
                      : (i == 2) ? P1 + (size_t)e * 3
                                 : P1 + (size_t)(e + 1) * 3;
      const float* lo = (i == 0) ? P0 + (size_t)e * 3
                      : (i == 1) ? P1 + (size_t)e * 3
                      : (i == 2) ? P0 + (size_t)(e + 1) * 3
                                 : P0 + (size_t)e * 3;
      const float dx = hi[0] - lo[0], dy = hi[1] - lo[1], dz = hi[2] - lo[2];
      v = sqrtf(dx * dx + dy * dy + dz * dz);
    }
    nrm[rr][i] = v;
  }
  __syncthreads();

  // --- h tile (swizzled store): chunk g8 of row rr -> (g8&24)|((g8+rr)&7) ---
  {
    const int g8 = tid & 31;
    const int strip = tid >> 5;
    float w1r[8][4], b1r[8];
    const float4* W14 = (const float4*)W1;
#pragma unroll
    for (int j = 0; j < 8; ++j) {
      const float4 w = W14[g8 * 8 + j];
      w1r[j][0] = w.x; w1r[j][1] = w.y; w1r[j][2] = w.z; w1r[j][3] = w.w;
      b1r[j] = b1[g8 * 8 + j];
    }
    for (int rr = strip; rr < 259; rr += 16) {
      const int e = n0 + rr - 2;
      const bool valid = (e >= 0) && (e < EE);
      const float nA = nrm[rr][0], nB = nrm[rr][1], nC = nrm[rr][2], nD = nrm[rr][3];
      u16x8 pack;
#pragma unroll
      for (int j = 0; j < 8; ++j) {
        float v = b1r[j] + nA * w1r[j][0] + nB * w1r[j][1] +
                  nC * w1r[j][2] + nD * w1r[j][3];
        v = (v >= 0.f) ? v : 0.2f * v;
        pack[j] = valid ? f2bf(v) : (u16)0;
      }
      const int cs = (g8 & 24) | ((g8 + rr) & 7);
      *(u16x8*)(hs + rr * 528 + (cs << 4)) = pack;
    }
  }
  __syncthreads();

  const f32x4 zero = {0.f, 0.f, 0.f, 0.f};
  f32x4 acc[8][4];
#pragma unroll
  for (int m = 0; m < 8; ++m)
#pragma unroll
    for (int nf = 0; nf < 4; ++nf) acc[m][nf] = zero;

  const char* mb = (const char*)Ma + (size_t)(wn * 64 + llo) * 64 + (size_t)lhi * 16;
  const int rb = wm * 128 + llo;
  const int lt = llo + lhi;

  bf16x8 pA0, pA1, pA2, pA3, pB0, pB1, pB2, pB3;
  pA0 = *(const bf16x8*)(mb);
  pA1 = *(const bf16x8*)(mb + 1024);
  pA2 = *(const bf16x8*)(mb + 2048);
  pA3 = *(const bf16x8*)(mb + 3072);

  bf16x8 afA0, afA1, afA2, afA3, afB0, afB1, afB2, afB3;
  {
    const char* ap = hs + rb * 528 + (((lt) & 7) << 4);
    afA0 = *(const bf16x8*)(ap);
    afA1 = *(const bf16x8*)(ap + 8448);
    afA2 = *(const bf16x8*)(ap + 16896);
    afA3 = *(const bf16x8*)(ap + 25344);
  }

#pragma unroll 1
  for (int s = 0; s < 32; s += 2) {
    const int tap = s >> 3;
    const int q = (s >> 1) & 3;
    const int swe = (lt + tap) & 7;
    const char* rowp = hs + (rb + tap) * 528 + (q << 7);
    const char* ape = rowp + (swe << 4);
    const char* apo = rowp + ((swe ^ 4) << 4);
    {
      const char* bp = mb + (size_t)(s + 1) * 16384;
      pB0 = *(const bf16x8*)(bp);
      pB1 = *(const bf16x8*)(bp + 1024);
      pB2 = *(const bf16x8*)(bp + 2048);
      pB3 = *(const bf16x8*)(bp + 3072);
      afB0 = *(const bf16x8*)(ape + 33792);
      afB1 = *(const bf16x8*)(ape + 42240);
      afB2 = *(const bf16x8*)(ape + 50688);
      afB3 = *(const bf16x8*)(ape + 59136);
      acc[0][0] = MM(pA0, afA0, acc[0][0]); acc[1][0] = MM(pA0, afA1, acc[1][0]);
      acc[2][0] = MM(pA0, afA2, acc[2][0]); acc[3][0] = MM(pA0, afA3, acc[3][0]);
      acc[0][1] = MM(pA1, afA0, acc[0][1]); acc[1][1] = MM(pA1, afA1, acc[1][1]);
      acc[2][1] = MM(pA1, afA2, acc[2][1]); acc[3][1] = MM(pA1, afA3, acc[3][1]);
      acc[0][2] = MM(pA2, afA0, acc[0][2]); acc[1][2] = MM(pA2, afA1, acc[1][2]);
      acc[2][2] = MM(pA2, afA2, acc[2][2]); acc[3][2] = MM(pA2, afA3, acc[3][2]);
      acc[0][3] = MM(pA3, afA0, acc[0][3]); acc[1][3] = MM(pA3, afA1, acc[1][3]);
      acc[2][3] = MM(pA3, afA2, acc[2][3]); acc[3][3] = MM(pA3, afA3, acc[3][3]);
      afA0 = *(const bf16x8*)(apo);
      afA1 = *(const bf16x8*)(apo + 8448);
      afA2 = *(const bf16x8*)(apo + 16896);
      afA3 = *(const bf16x8*)(apo + 25344);
      acc[4][0] = MM(pA0, afB0, acc[4][0]); acc[5][0] = MM(pA0, afB1, acc[5][0]);
      acc[6][0] = MM(pA0, afB2, acc[6][0]); acc[7][0] = MM(pA0, afB3, acc[7][0]);
      acc[4][1] = MM(pA1, afB0, acc[4][1]); acc[5][1] = MM(pA1, afB1, acc[5][1]);
      acc[6][1] = MM(pA1, afB2, acc[6][1]); acc[7][1] = MM(pA1, afB3, acc[7][1]);
      acc[4][2] = MM(pA2, afB0, acc[4][2]); acc[5][2] = MM(pA2, afB1, acc[5][2]);
      acc[6][2] = MM(pA2, afB2, acc[6][2]); acc[7][2] = MM(pA2, afB3, acc[7][2]);
      acc[4][3] = MM(pA3, afB0, acc[4][3]); acc[5][3] = MM(pA3, afB1, acc[5][3]);
      acc[6][3] = MM(pA3, afB2, acc[6][3]); acc[7][3] = MM(pA3, afB3, acc[7][3]);
    }
    {
      const int s2 = (s + 2) & 31;
      const char* bp = mb + (size_t)s2 * 16384;
      pA0 = *(const bf16x8*)(bp);
      pA1 = *(const bf16x8*)(bp + 1024);
      pA2 = *(const bf16x8*)(bp + 2048);
      pA3 = *(const bf16x8*)(bp + 3072);
      afB0 = *(const bf16x8*)(apo + 33792);
      afB1 = *(const bf16x8*)(apo + 42240);
      afB2 = *(const bf16x8*)(apo + 50688);
      afB3 = *(const bf16x8*)(apo + 59136);
      acc[0][0] = MM(pB0, afA0, acc[0][0]); acc[1][0] = MM(pB0, afA1, acc[1][0]);
      acc[2][0] = MM(pB0, afA2, acc[2][0]); acc[3][0] = MM(pB0, afA3, acc[3][0]);
      acc[0][1] = MM(pB1, afA0, acc[0][1]); acc[1][1] = MM(pB1, afA1, acc[1][1]);
      acc[2][1] = MM(pB1, afA2, acc[2][1]); acc[3][1] = MM(pB1, afA3, acc[3][1]);
      acc[0][2] = MM(pB2, afA0, acc[0][2]); acc[1][2] = MM(pB2, afA1, acc[1][2]);
      acc[2][2] = MM(pB2, afA2, acc[2][2]); acc[3][2] = MM(pB2, afA3, acc[3][2]);
      acc[0][3] = MM(pB3, afA0, acc[0][3]); acc[1][3] = MM(pB3, afA1, acc[1][3]);
      acc[2][3] = MM(pB3, afA2, acc[2][3]); acc[3][3] = MM(pB3, afA3, acc[3][3]);
      {
        const int tap2 = s2 >> 3;
        const int q2 = (s2 >> 1) & 3;
        const char* ap2 = hs + (rb + tap2) * 528 + (q2 << 7) +
                          ((((lt + tap2) & 7)) << 4);
        afA0 = *(const bf16x8*)(ap2);
        afA1 = *(const bf16x8*)(ap2 + 8448);
        afA2 = *(const bf16x8*)(ap2 + 16896);
        afA3 = *(const bf16x8*)(ap2 + 25344);
      }
      acc[4][0] = MM(pB0, afB0, acc[4][0]); acc[5][0] = MM(pB0, afB1, acc[5][0]);
      acc[6][0] = MM(pB0, afB2, acc[6][0]); acc[7][0] = MM(pB0, afB3, acc[7][0]);
      acc[4][1] = MM(pB1, afB0, acc[4][1]); acc[5][1] = MM(pB1, afB1, acc[5][1]);
      acc[6][1] = MM(pB1, afB2, acc[6][1]); acc[7][1] = MM(pB1, afB3, acc[7][1]);
      acc[4][2] = MM(pB2, afB0, acc[4][2]); acc[5][2] = MM(pB2, afB1, acc[5][2]);
      acc[6][2] = MM(pB2, afB2, acc[6][2]); acc[7][2] = MM(pB2, afB3, acc[7][2]);
      acc[4][3] = MM(pB3, afB0, acc[4][3]); acc[5][3] = MM(pB3, afB1, acc[5][3]);
      acc[6][3] = MM(pB3, afB2, acc[6][3]); acc[7][3] = MM(pB3, afB3, acc[7][3]);
    }
  }

#pragma unroll
  for (int m = 0; m < 8; ++m) {
    const int node = n0 + wm * 128 + m * 16 + llo;
    float* orow = out + ((size_t)b * NN + node) * AD;
    const bool edge = (node <= 1) | (node >= NN - 2);
#pragma unroll
    for (int nf = 0; nf < 4; ++nf) {
      const int o0 = wn * 64 + nf * 16 + lhi * 4;
      float bx = bias_all[o0], by = bias_all[o0 + 1],
            bz = bias_all[o0 + 2], bw = bias_all[o0 + 3];
      if (edge) {
        const float* k0 = bk + o0;
        const float* k1 = bk + 256 + o0;
        const float* k2 = bk + 512 + o0;
        const float* k3 = bk + 768 + o0;
        if (node == 0) {
          bx -= k0[0] + k1[0]; by -= k0[1] + k1[1];
          bz -= k0[2] + k1[2]; bw -= k0[3] + k1[3];
        } else if (node == 1) {
          bx -= k0[0]; by -= k0[1]; bz -= k0[2]; bw -= k0[3];
        } else if (node == NN - 2) {
          bx -= k3[0]; by -= k3[1]; bz -= k3[2]; bw -= k3[3];
        } else {
          bx -= k2[0] + k3[0]; by -= k2[1] + k3[1];
          bz -= k2[2] + k3[2]; bw -= k2[3] + k3[3];
        }
      }
      f32x4 st;
      st[0] = acc[m][nf][0] + bx;
      st[1] = acc[m][nf][1] + by;
      st[2] = acc[m][nf][2] + bz;
      st[3] = acc[m][nf][3] + bw;
      __builtin_nontemporal_store(st, (f32x4*)(orow + o0));
    }
  }
}

// ---------------------------------------------------------------------------
// vec_path: R13's verified fused-vec-phase code as a standalone kernel.
// 256 nodes x 128 o per block (512 thr, 64 nodes/thread, sliding window),
// NT stores. grid = 16*32 = 512, block = 512.
// ---------------------------------------------------------------------------
__global__ __launch_bounds__(512) void vec_path(const float* __restrict__ p0,
                                                const float* __restrict__ p1,
                                                const float* __restrict__ Mw,
                                                float* __restrict__ out) {
  const int tid = threadIdx.x;
  const int b = blockIdx.x >> 5;
  const int n0 = (blockIdx.x & 31) * 256;
  const size_t pbase = (size_t)b * NN * 3;
  const int o = tid & 127, ng = tid >> 7;
  const int nstart = n0 + ng * 64;
  const float4* Mw4 = (const float4*)Mw;
  const float4 w0 = Mw4[o], w1 = Mw4[128 + o],
               w2 = Mw4[256 + o], w3 = Mw4[384 + o];
  float* vb = out + 33554432ULL + (((size_t)b * NN + nstart) * 128 + o) * 3;
  const float* P0 = p0 + pbase;
  const float* P1 = p1 + pbase;
  float Ra[8][3], Rp[8][3];
#pragma unroll
  for (int r = 0; r < 8; ++r) {
    int row = nstart - 2 + r;
    row = row < 0 ? 0 : (row > NN - 1 ? NN - 1 : row);
    const float* a = P0 + (size_t)row * 3;
    const float* p = P1 + (size_t)row * 3;
    Ra[r][0] = a[0]; Ra[r][1] = a[1]; Ra[r][2] = a[2];
    Rp[r][0] = p[0]; Rp[r][1] = p[1]; Rp[r][2] = p[2];
  }
#pragma unroll 1
  for (int jc = 0; jc < 16; ++jc) {
    const int nb = nstart + jc * 4;
#pragma unroll
    for (int jj = 0; jj < 4; ++jj) {
      const int n = nb + jj;
      float r0 = 0.f, r1 = 0.f, r2 = 0.f;
#pragma unroll
      for (int k = 0; k < 4; ++k) {
        if (n + k >= 2 && n + k <= NN) {   // 0 <= e <= EE-1
          const float4 w = (k == 0) ? w0 : (k == 1) ? w1 : (k == 2) ? w2 : w3;
          r0 += w.x * Ra[jj + k][0] + w.y * Ra[jj + k + 1][0] +
                w.z * Rp[jj + k][0] + w.w * Rp[jj + k + 1][0];
          r1 += w.x * Ra[jj + k][1] + w.y * Ra[jj + k + 1][1] +
                w.z * Rp[jj + k][1] + w.w * Rp[jj + k + 1][1];
          r2 += w.x * Ra[jj + k][2] + w.y * Ra[jj + k + 1][2] +
                w.z * Rp[jj + k][2] + w.w * Rp[jj + k + 1][2];
        }
      }
      float* dst = vb + (size_t)(jc * 4 + jj) * 384;
      __builtin_nontemporal_store(r0, dst + 0);
      __builtin_nontemporal_store(r1, dst + 1);
      __builtin_nontemporal_store(r2, dst + 2);
    }
    if (jc < 15) {   // slide window by 4 rows
#pragma unroll
      for (int r = 0; r < 4; ++r) {
        Ra[r][0] = Ra[r + 4][0]; Ra[r][1] = Ra[r + 4][1]; Ra[r][2] = Ra[r + 4][2];
        Rp[r][0] = Rp[r + 4][0]; Rp[r][1] = Rp[r + 4][1]; Rp[r][2] = Rp[r + 4][2];
      }
#pragma unroll
      for (int r = 4; r < 8; ++r) {
        int row = nb + 2 + r;   // rows nb+6 .. nb+9
        row = row > NN - 1 ? NN - 1 : row;
        const float* a = P0 + (size_t)row * 3;
        const float* p = P1 + (size_t)row * 3;
        Ra[r][0] = a[0]; Ra[r][1] = a[1]; Ra[r][2] = a[2];
        Rp[r][0] = p[0]; Rp[r][1] = p[1]; Rp[r][2] = p[2];
      }
    }
  }
}

// ---------------------------------------------------------------------------
extern "C" void kernel_launch(void* const* d_in, const int* in_sizes, int n_in,
                              void* d_out, int out_size, void* d_ws, size_t ws_size,
                              hipStream_t stream) {
  const float* pos_0 = (const float*)d_in[0];
  const float* pos_1 = (const float*)d_in[1];
  const float* W_v = (const float*)d_in[2];
  const float* W1 = (const float*)d_in[3];
  const float* b1 = (const float*)d_in[4];
  const float* W2 = (const float*)d_in[5];
  const float* b2 = (const float*)d_in[6];
  const float* K_a = (const float*)d_in[7];
  const float* b_a = (const float*)d_in[8];
  const float* K_v = (const float*)d_in[9];
  float* out = (float*)d_out;
  char* ws = (char*)d_ws;

  const size_t MA_BYTES = (size_t)32 * 256 * 32 * 2;    // 524,288
  u16* Ma = (u16*)(ws);
  float* bk = (float*)(ws + MA_BYTES);
  float* bias_all = (float*)(ws + MA_BYTES + 4096);
  float* Mw = (float*)(ws + MA_BYTES + 4096 + 1024);

  prep_ma<<<dim3(256), dim3(256), 0, stream>>>(W2, b2, K_a, b_a, W_v, K_v,
                                               Ma, bk, bias_all, Mw);
  gemm_a<<<dim3(512), dim3(512), 0, stream>>>(pos_0, pos_1, W1, b1, Ma,
                                              bias_all, bk, out);
  vec_path<<<dim3(512), dim3(512), 0, stream>>>(pos_0, pos_1, Mw, out);
}